// Round 1
// baseline (1118.765 us; speedup 1.0000x reference)
//
#include <hip/hip_runtime.h>
#include <hip/hip_bf16.h>
#include <math.h>

typedef __hip_bfloat16 bf16;
typedef __attribute__((ext_vector_type(8))) short short8;
typedef __attribute__((ext_vector_type(4))) float f32x4;

#define DEV __device__ __forceinline__

DEV void gload_lds16(const bf16* g, bf16* l) {
    __builtin_amdgcn_global_load_lds(
        (__attribute__((address_space(1))) void*)(g),
        (__attribute__((address_space(3))) void*)(l), 16, 0, 0);
}

// ---------------------------------------------------------------------------
// GEMM: C[M,N](bf16) = act(A[M,K] * Bt[N,K]^T + bias)
// Bt is the weight matrix pre-transposed to [N][K] row-major.
// ACT: 0 = none, 1 = ELU.  DUAL: C = sigmoid(A*B1+bias1) * (A*B2+bias2)
// Tile: BM=BN=128, BK=32. 256 threads = 4 waves (2x2), each wave 64x64 out.
// grid = (N/128, M/128, batch)
// ---------------------------------------------------------------------------
template<int ACT, bool DUAL>
__global__ __launch_bounds__(256, 2)
void gemm_k(const bf16* __restrict__ A, int lda, long aBatch,
            const bf16* __restrict__ B1p, const bf16* __restrict__ B2p,
            int ldb, long bBatch,
            const float* __restrict__ bias1p, const float* __restrict__ bias2p,
            long biasBatch,
            bf16* __restrict__ C, int ldc, long cBatch, int K)
{
    const int bz = blockIdx.z;
    A   += (long)bz * aBatch;
    const bf16* B1 = B1p + (long)bz * bBatch;
    const float* bias1 = bias1p + (long)bz * biasBatch;
    C   += (long)bz * cBatch;
    const bf16* B2 = nullptr;
    const float* bias2 = nullptr;
    if constexpr (DUAL) {
        B2 = B2p + (long)bz * bBatch;
        bias2 = bias2p + (long)bz * biasBatch;
    }

    const int rowBase = blockIdx.y * 128;
    const int colBase = blockIdx.x * 128;

    __shared__ bf16 As[128 * 32];
    __shared__ bf16 Bs[128 * 32];
    __shared__ bf16 Bs2[DUAL ? 128 * 32 : 8];

    const int tid  = threadIdx.x;
    const int wid  = tid >> 6;
    const int lane = tid & 63;
    const int wr = wid >> 1, wc = wid & 1;     // 2x2 wave grid
    const int lr = lane & 15, lg = lane >> 4;  // frag row/col, k-group

    f32x4 acc[4][4] = {};
    f32x4 acc2[4][4] = {};

    // staging: tile is 128x32 bf16 = 8KB, row-major, k contiguous.
    // 2 issues of 4KB; per issue each wave covers 1KB (64 lanes x 16B).
    const int e0 = wid * 512 + lane * 8;   // element offset within tile, issue 0
    const int sr = e0 >> 5;                // row within tile
    const int sc = e0 & 31;                // col (k) within tile

    const bf16* a0 = A  + (long)(rowBase + sr)      * lda + sc;
    const bf16* a1 = A  + (long)(rowBase + sr + 64) * lda + sc;
    const bf16* b0 = B1 + (long)(colBase + sr)      * ldb + sc;
    const bf16* b1 = B1 + (long)(colBase + sr + 64) * ldb + sc;
    const bf16* d0 = nullptr; const bf16* d1 = nullptr;
    if constexpr (DUAL) {
        d0 = B2 + (long)(colBase + sr)      * ldb + sc;
        d1 = B2 + (long)(colBase + sr + 64) * ldb + sc;
    }

    bf16* AsW = As + wid * 512;   // wave-uniform LDS bases (HW adds lane*16B)
    bf16* BsW = Bs + wid * 512;
    bf16* Bs2W = nullptr;
    if constexpr (DUAL) Bs2W = Bs2 + wid * 512;

    for (int k0 = 0; k0 < K; k0 += 32) {
        gload_lds16(a0 + k0, AsW);
        gload_lds16(a1 + k0, AsW + 2048);
        gload_lds16(b0 + k0, BsW);
        gload_lds16(b1 + k0, BsW + 2048);
        if constexpr (DUAL) {
            gload_lds16(d0 + k0, Bs2W);
            gload_lds16(d1 + k0, Bs2W + 2048);
        }
        __syncthreads();

        short8 a[4], bb[4], b2[4];
        #pragma unroll
        for (int m = 0; m < 4; m++)
            a[m] = *(const short8*)(As + (wr * 64 + m * 16 + lr) * 32 + lg * 8);
        #pragma unroll
        for (int n = 0; n < 4; n++)
            bb[n] = *(const short8*)(Bs + (wc * 64 + n * 16 + lr) * 32 + lg * 8);
        if constexpr (DUAL) {
            #pragma unroll
            for (int n = 0; n < 4; n++)
                b2[n] = *(const short8*)(Bs2 + (wc * 64 + n * 16 + lr) * 32 + lg * 8);
        }

        #pragma unroll
        for (int m = 0; m < 4; m++) {
            #pragma unroll
            for (int n = 0; n < 4; n++) {
                acc[m][n] = __builtin_amdgcn_mfma_f32_16x16x32_bf16(a[m], bb[n], acc[m][n], 0, 0, 0);
                if constexpr (DUAL)
                    acc2[m][n] = __builtin_amdgcn_mfma_f32_16x16x32_bf16(a[m], b2[n], acc2[m][n], 0, 0, 0);
            }
        }
        __syncthreads();
    }

    // epilogue: C/D layout col = lane&15, row = (lane>>4)*4 + i  (m89-verified)
    #pragma unroll
    for (int m = 0; m < 4; m++) {
        const int row = rowBase + wr * 64 + m * 16 + lg * 4;
        #pragma unroll
        for (int n = 0; n < 4; n++) {
            const int col = colBase + wc * 64 + n * 16 + lr;
            const float bv1 = bias1[col];
            float bv2 = 0.f;
            if constexpr (DUAL) bv2 = bias2[col];
            #pragma unroll
            for (int i = 0; i < 4; i++) {
                float v = acc[m][n][i] + bv1;
                if constexpr (ACT == 1) v = v > 0.f ? v : expm1f(v);
                if constexpr (DUAL) {
                    float v2 = acc2[m][n][i] + bv2;
                    v = v2 / (1.f + expf(-v));   // sigmoid(v) * v2
                }
                C[(long)(row + i) * ldc + col] = __float2bfloat16(v);
            }
        }
    }
}

// ---------------------------------------------------------------------------
// fp32 -> bf16 convert (vectorized, 8 elems/thread)
// ---------------------------------------------------------------------------
__global__ __launch_bounds__(256)
void cvt_k(const float* __restrict__ in, bf16* __restrict__ out)
{
    const long i = ((long)blockIdx.x * 256 + threadIdx.x) * 8;
    float4 u = *(const float4*)(in + i);
    float4 v = *(const float4*)(in + i + 4);
    bf16 t[8];
    t[0] = __float2bfloat16(u.x); t[1] = __float2bfloat16(u.y);
    t[2] = __float2bfloat16(u.z); t[3] = __float2bfloat16(u.w);
    t[4] = __float2bfloat16(v.x); t[5] = __float2bfloat16(v.y);
    t[6] = __float2bfloat16(v.z); t[7] = __float2bfloat16(v.w);
    *(short8*)(out + i) = *(short8*)t;
}

// ---------------------------------------------------------------------------
// transpose + convert: in f32 [R][R] row-major -> out bf16 [R][R] transposed.
// grid.z = widx*nsub + sub  (sub-matrix batching for the per-variable weights)
// block = 256 threads treated as (32,8), 32x32 tiles.
// ---------------------------------------------------------------------------
struct TPtrs { const float* s[4]; bf16* d[4]; };

__global__ __launch_bounds__(256)
void transpose_cvt_k(TPtrs p, int R, int nsub)
{
    const int z = blockIdx.z;
    const int widx = z / nsub, sub = z - widx * nsub;
    const float* __restrict__ in = p.s[widx] + (long)sub * R * R;
    bf16* __restrict__ outp = p.d[widx] + (long)sub * R * R;

    __shared__ float tile[32][33];
    const int c0 = blockIdx.x * 32, r0 = blockIdx.y * 32;
    const int tx = threadIdx.x & 31, ty = threadIdx.x >> 5;
    #pragma unroll
    for (int i = 0; i < 4; i++)
        tile[ty + i * 8][tx] = in[(long)(r0 + ty + i * 8) * R + c0 + tx];
    __syncthreads();
    #pragma unroll
    for (int i = 0; i < 4; i++)
        outp[(long)(c0 + ty + i * 8) * R + r0 + tx] = __float2bfloat16(tile[tx][ty + i * 8]);
}

// ---------------------------------------------------------------------------
// block reduce (256 threads) of two values, result broadcast to all threads
// ---------------------------------------------------------------------------
DEV float2 block_reduce2_bcast(float a, float b, float* lds)
{
    const int lane = threadIdx.x & 63, wid = threadIdx.x >> 6;
    #pragma unroll
    for (int off = 32; off > 0; off >>= 1) {
        a += __shfl_down(a, off, 64);
        b += __shfl_down(b, off, 64);
    }
    __syncthreads();
    if (lane == 0) { lds[wid] = a; lds[wid + 4] = b; }
    __syncthreads();
    float2 r;
    r.x = lds[0] + lds[1] + lds[2] + lds[3];
    r.y = lds[4] + lds[5] + lds[6] + lds[7];
    return r;
}

// ---------------------------------------------------------------------------
// c = LN(x_flat + g) over 4096 feats; w = softmax over n (16) per (b, d)
// one block per row b; thread d owns all 16 n-slots -> softmax is thread-local
// ---------------------------------------------------------------------------
__global__ __launch_bounds__(256)
void ln_softmax_k(const float* __restrict__ x, const bf16* __restrict__ g,
                  const float* __restrict__ gamma, const float* __restrict__ beta,
                  bf16* __restrict__ w)
{
    const int b = blockIdx.x, d = threadIdx.x;
    const long base = (long)b * 4096;
    __shared__ float red[8];

    float s[16];
    float sum = 0.f, sumsq = 0.f;
    #pragma unroll
    for (int n = 0; n < 16; n++) {
        float v = x[base + n * 256 + d] + __bfloat162float(g[base + n * 256 + d]);
        s[n] = v; sum += v; sumsq += v * v;
    }
    float2 t = block_reduce2_bcast(sum, sumsq, red);
    const float mean = t.x * (1.f / 4096.f);
    const float var  = t.y * (1.f / 4096.f) - mean * mean;
    const float rstd = rsqrtf(var + 1e-5f);

    float mx = -1e30f;
    #pragma unroll
    for (int n = 0; n < 16; n++) {
        float c = (s[n] - mean) * rstd * gamma[n * 256 + d] + beta[n * 256 + d];
        s[n] = c; mx = fmaxf(mx, c);
    }
    float denom = 0.f;
    #pragma unroll
    for (int n = 0; n < 16; n++) { float e = expf(s[n] - mx); s[n] = e; denom += e; }
    const float rden = 1.f / denom;
    #pragma unroll
    for (int n = 0; n < 16; n++)
        w[base + n * 256 + d] = __float2bfloat16(s[n] * rden);
}

// ---------------------------------------------------------------------------
// out[b,d] = sum_n w[b,n,d] * LN_n(x[b,n,:] + gv[b,n,:])[d]
// one block per b; 16 sequential block-LNs over 256
// ---------------------------------------------------------------------------
__global__ __launch_bounds__(256)
void combine_k(const float* __restrict__ x, const bf16* __restrict__ gv,
               const bf16* __restrict__ w,
               const float* __restrict__ vlng, const float* __restrict__ vlnb,
               float* __restrict__ out)
{
    const int b = blockIdx.x, d = threadIdx.x;
    const long base = (long)b * 4096;
    __shared__ float red[8];
    float acc = 0.f;
    for (int n = 0; n < 16; n++) {
        float v = x[base + n * 256 + d] + __bfloat162float(gv[base + n * 256 + d]);
        float2 t = block_reduce2_bcast(v, v * v, red);
        const float mean = t.x * (1.f / 256.f);
        const float var  = t.y * (1.f / 256.f) - mean * mean;
        const float yv = (v - mean) * rsqrtf(var + 1e-5f) * vlng[n * 256 + d] + vlnb[n * 256 + d];
        acc += __bfloat162float(w[base + n * 256 + d]) * yv;
    }
    out[(long)b * 256 + d] = acc;
}

// ---------------------------------------------------------------------------
extern "C" void kernel_launch(void* const* d_in, const int* in_sizes, int n_in,
                              void* d_out, int out_size, void* d_ws, size_t ws_size,
                              hipStream_t stream)
{
    const float* x    = (const float*)d_in[0];
    const float* vW2  = (const float*)d_in[1];
    const float* vb2  = (const float*)d_in[2];
    const float* vW1  = (const float*)d_in[3];
    const float* vb1  = (const float*)d_in[4];
    const float* vW4  = (const float*)d_in[5];
    const float* vb4  = (const float*)d_in[6];
    const float* vW5  = (const float*)d_in[7];
    const float* vb5  = (const float*)d_in[8];
    const float* vlng = (const float*)d_in[9];
    const float* vlnb = (const float*)d_in[10];
    const float* cW2  = (const float*)d_in[11];
    const float* cb2  = (const float*)d_in[12];
    const float* cW1  = (const float*)d_in[13];
    const float* cb1  = (const float*)d_in[14];
    const float* cW4  = (const float*)d_in[15];
    const float* cb4  = (const float*)d_in[16];
    const float* cW5  = (const float*)d_in[17];
    const float* cb5  = (const float*)d_in[18];
    const float* clng = (const float*)d_in[19];
    const float* clnb = (const float*)d_in[20];
    float* out = (float*)d_out;
    (void)n_in; (void)out_size; (void)ws_size;

    const int NB = in_sizes[0] / 4096;       // batch rows (4096)
    const long XF = (long)NB * 4096;         // total x elements

    char* ws = (char*)d_ws;
    size_t off = 0;
    auto alloc = [&](size_t bytes) {
        char* p = ws + off;
        off += (bytes + 255) & ~(size_t)255;
        return p;
    };
    bf16* xb   = (bf16*)alloc(XF * 2);
    bf16* cW2t = (bf16*)alloc(4096L * 4096 * 2);
    bf16* cW1t = (bf16*)alloc(4096L * 4096 * 2);
    bf16* cW4t = (bf16*)alloc(4096L * 4096 * 2);
    bf16* cW5t = (bf16*)alloc(4096L * 4096 * 2);
    bf16* vW2t = (bf16*)alloc(16L * 256 * 256 * 2);
    bf16* vW1t = (bf16*)alloc(16L * 256 * 256 * 2);
    bf16* vW4t = (bf16*)alloc(16L * 256 * 256 * 2);
    bf16* vW5t = (bf16*)alloc(16L * 256 * 256 * 2);
    bf16* bufA = (bf16*)alloc(XF * 2);
    bf16* bufB = (bf16*)alloc(XF * 2);
    bf16* bufW = (bf16*)alloc(XF * 2);

    const int MB = NB / 128;                 // 32 row-tiles

    // 1. x -> bf16
    cvt_k<<<dim3((unsigned)(XF / 2048)), 256, 0, stream>>>(x, xb);

    // 2. big concat weights: transpose + convert ([K][N] f32 -> [N][K] bf16)
    TPtrs pb;
    pb.s[0] = cW2; pb.s[1] = cW1; pb.s[2] = cW4; pb.s[3] = cW5;
    pb.d[0] = cW2t; pb.d[1] = cW1t; pb.d[2] = cW4t; pb.d[3] = cW5t;
    transpose_cvt_k<<<dim3(128, 128, 4), 256, 0, stream>>>(pb, 4096, 1);

    // 3. per-variable weights: per-n transpose + convert
    TPtrs pv;
    pv.s[0] = vW2; pv.s[1] = vW1; pv.s[2] = vW4; pv.s[3] = vW5;
    pv.d[0] = vW2t; pv.d[1] = vW1t; pv.d[2] = vW4t; pv.d[3] = vW5t;
    transpose_cvt_k<<<dim3(8, 8, 64), 256, 0, stream>>>(pv, 256, 16);

    // 4. h = elu(xb @ cW2 + cb2) -> bufA
    gemm_k<1, false><<<dim3(32, MB, 1), 256, 0, stream>>>(
        xb, 4096, 0, cW2t, nullptr, 4096, 0, cb2, nullptr, 0, bufA, 4096, 0, 4096);
    // 5. e1 = bufA @ cW1 + cb1 -> bufB
    gemm_k<0, false><<<dim3(32, MB, 1), 256, 0, stream>>>(
        bufA, 4096, 0, cW1t, nullptr, 4096, 0, cb1, nullptr, 0, bufB, 4096, 0, 4096);
    // 6. g = sigmoid(bufB@cW4+cb4) * (bufB@cW5+cb5) -> bufA
    gemm_k<0, true><<<dim3(32, MB, 1), 256, 0, stream>>>(
        bufB, 4096, 0, cW4t, cW5t, 4096, 0, cb4, cb5, 0, bufA, 4096, 0, 4096);
    // 7. c = LN(x_flat + g); w = softmax_n(c) -> bufW
    ln_softmax_k<<<dim3(NB), 256, 0, stream>>>(x, bufA, clng, clnb, bufW);

    // 8. hv = elu(x @ vW2 + vb2) -> bufB    (batched over n)
    gemm_k<1, false><<<dim3(2, MB, 16), 256, 0, stream>>>(
        xb, 4096, 256, vW2t, nullptr, 256, 65536, vb2, nullptr, 256, bufB, 4096, 256, 256);
    // 9. e1v = bufB @ vW1 + vb1 -> bufA
    gemm_k<0, false><<<dim3(2, MB, 16), 256, 0, stream>>>(
        bufB, 4096, 256, vW1t, nullptr, 256, 65536, vb1, nullptr, 256, bufA, 4096, 256, 256);
    // 10. gv = sigmoid(bufA@vW4+vb4)*(bufA@vW5+vb5) -> bufB
    gemm_k<0, true><<<dim3(2, MB, 16), 256, 0, stream>>>(
        bufA, 4096, 256, vW4t, vW5t, 256, 65536, vb4, vb5, 256, bufB, 4096, 256, 256);

    // 11. yv = LN_n(x + gv); out = sum_n w * yv
    combine_k<<<dim3(NB), 256, 0, stream>>>(x, bufB, bufW, vlng, vlnb, out);
}

// Round 2
// 1068.739 us; speedup vs baseline: 1.0468x; 1.0468x over previous
//
#include <hip/hip_runtime.h>
#include <hip/hip_bf16.h>
#include <math.h>
#include <type_traits>

typedef __hip_bfloat16 bf16;
typedef __attribute__((ext_vector_type(8))) short short8;
typedef __attribute__((ext_vector_type(4))) float f32x4;

#define DEV __device__ __forceinline__

template<int V> using IC = std::integral_constant<int, V>;

DEV void gload_lds16(const bf16* g, bf16* l) {
    __builtin_amdgcn_global_load_lds(
        (const __attribute__((address_space(1))) void*)(g),
        (__attribute__((address_space(3))) void*)(l), 16, 0, 0);
}

#define VMW(n) do { asm volatile("s_waitcnt vmcnt(" #n ")" ::: "memory"); \
                    __builtin_amdgcn_sched_barrier(0); } while (0)

// ---------------------------------------------------------------------------
// 256x256 tile, BK=64, 8 waves (2M x 4N), deep-pipelined 4-phase/K-tile
// schedule with counted vmcnt (T2 st_16x32 swizzle + T3/T4 + T5).
// C[M,N](bf16) = act(A[M,K] * Bt[N,K]^T + bias); Bt pre-transposed [N][K].
// grid = (N/256, M/256, batch), 512 threads, 128KB dynamic LDS.
// ---------------------------------------------------------------------------
template<int ACT>   // 0 = none, 1 = ELU
__global__ __launch_bounds__(512, 2)
void gemm256_k(const bf16* __restrict__ Am, int lda, long aBatch,
               const bf16* __restrict__ Bm, int ldb, long bBatch,
               const float* __restrict__ biasp, long biasBatch,
               bf16* __restrict__ Cm, int ldc, long cBatch, int K)
{
    extern __shared__ char lds[];
    const int bz = blockIdx.z;
    const bf16* A = Am + (long)bz * aBatch;
    const bf16* B = Bm + (long)bz * bBatch;
    const float* bias = biasp + (long)bz * biasBatch;
    bf16* C = Cm + (long)bz * cBatch;

    // T1: bijective XCD swizzle on the x-y grid (nwg multiple of 8 here)
    const int nwg = gridDim.x * gridDim.y;
    int flat = blockIdx.y * gridDim.x + blockIdx.x;
    if ((nwg & 7) == 0 && nwg >= 8) flat = (flat & 7) * (nwg >> 3) + (flat >> 3);
    const int bx = flat % gridDim.x, by = flat / gridDim.x;
    const int rowBase = by * 256, colBase = bx * 256;

    const int tid = threadIdx.x;
    const int wid = tid >> 6, lane = tid & 63;
    const int wr = wid >> 2, wc = wid & 3;     // 2x4 wave grid
    const int lr = lane & 15, lg = lane >> 4;

    // ---- staging source mapping (inverse st_16x32 swizzle on global src) ----
    // LDS linear byte P = h*16384 + j*8192 + tid*16 holds logical element at
    // P ^ (((P>>9)&1)<<5);  bit9 == (r & 8).
    const int r     = (tid >> 2) & 15;
    const int cbyte = (tid & 3) * 16;
    const int c0    = ((r & 8) ? (cbyte ^ 32) : cbyte) >> 1;   // elements
    const int srow  = (wid >> 1) * 16 + r;                     // + h*128 + j*64
    const int scol  = (wid & 1) * 32 + c0;

    const bf16* Ap = A + (long)(rowBase + srow) * lda + scol;
    const bf16* Bp = B + (long)(colBase + srow) * ldb + scol;

    // ---- swizzled ds_read frag bases (bytes within operand buffer) ----
    const int cb  = (lr & 8) ? ((lg * 16) ^ 32) : (lg * 16);
    const int aRd = wr * 8192 + lr * 64 + cb;
    const int bRd = wc * 4096 + lr * 64 + cb;

    f32x4  acc[2][2][4][2] = {};   // [qm][qn][mi][ni]
    short8 aF[2][4][2];            // [qm][mi][ks]
    short8 bF[2][2][2];            // [qn][ni][ks]

    const int T = K >> 6;

    auto stageA = [&](int tt, int h) {
        bf16* d = (bf16*)(lds + (tt & 1) * 32768 + h * 16384 + wid * 1024);
        const bf16* s = Ap + tt * 64 + (long)h * 128 * lda;
        gload_lds16(s, d);
        gload_lds16(s + (long)64 * lda, (bf16*)((char*)d + 8192));
    };
    auto stageB = [&](int tt, int h) {
        bf16* d = (bf16*)(lds + 65536 + (tt & 1) * 32768 + h * 16384 + wid * 1024);
        const bf16* s = Bp + tt * 64 + (long)h * 128 * ldb;
        gload_lds16(s, d);
        gload_lds16(s + (long)64 * ldb, (bf16*)((char*)d + 8192));
    };
    auto readA = [&](int tt, auto qmc) {
        constexpr int qm = decltype(qmc)::value;
        const char* base = lds + (tt & 1) * 32768 + qm * 16384 + aRd;
        #pragma unroll
        for (int mi = 0; mi < 4; mi++)
            #pragma unroll
            for (int ks = 0; ks < 2; ks++)
                aF[qm][mi][ks] = *(const short8*)(base + mi * 2048 + ks * 1024);
    };
    auto readB = [&](int tt, auto qnc) {
        constexpr int qn = decltype(qnc)::value;
        const char* base = lds + 65536 + (tt & 1) * 32768 + qn * 16384 + bRd;
        #pragma unroll
        for (int ni = 0; ni < 2; ni++)
            #pragma unroll
            for (int ks = 0; ks < 2; ks++)
                bF[qn][ni][ks] = *(const short8*)(base + ni * 2048 + ks * 1024);
    };
    auto mma = [&](auto qmc, auto qnc) {
        constexpr int qm = decltype(qmc)::value;
        constexpr int qn = decltype(qnc)::value;
        __builtin_amdgcn_s_setprio(1);
        #pragma unroll
        for (int mi = 0; mi < 4; mi++)
          #pragma unroll
          for (int ni = 0; ni < 2; ni++)
            #pragma unroll
            for (int ks = 0; ks < 2; ks++)
              acc[qm][qn][mi][ni] = __builtin_amdgcn_mfma_f32_16x16x32_bf16(
                  aF[qm][mi][ks], bF[qn][ni][ks], acc[qm][qn][mi][ni], 0, 0, 0);
        __builtin_amdgcn_s_setprio(0);
    };
    auto bar = [&]() {
        __builtin_amdgcn_sched_barrier(0);
        __builtin_amdgcn_s_barrier();
        __builtin_amdgcn_sched_barrier(0);
    };

    // ---- prologue: issue A0(0),B0(0),A1(0),B1(0),A0(1); wait 2 oldest ----
    stageA(0, 0); stageB(0, 0); stageA(0, 1); stageB(0, 1);
    if (T > 1) stageA(1, 0);
    VMW(6);
    bar();
    readA(0, IC<0>{}); readB(0, IC<0>{});

    // ---- main loop: 4 phases per K-tile, snake quadrant order ----
    for (int t = 0; t < T; t++) {
        const bool last  = (t == T - 1);
        const bool last2 = (t == T - 2);
        // phase 0: MFMA(A0,B0); read A1(t); stage B0(t+1)
        if (!last) stageB(t + 1, 0);
        if (!last) { VMW(6); } else { VMW(2); }
        bar();
        readA(t, IC<1>{});
        mma(IC<0>{}, IC<0>{});
        bar();
        // phase 1: MFMA(A1,B0); read B1(t); stage A1(t+1)
        if (!last) stageA(t + 1, 1);
        if (!last) { VMW(6); } else { VMW(0); }
        bar();
        readB(t, IC<1>{});
        mma(IC<1>{}, IC<0>{});
        bar();
        // phase 2: MFMA(A1,B1); stage B1(t+1); no new reads, no wait
        if (!last) stageB(t + 1, 1);
        bar();
        mma(IC<1>{}, IC<1>{});
        bar();
        // phase 3: MFMA(A0,B1); stage A0(t+2); then read A0,B0 of t+1
        if (t + 2 < T) stageA(t + 2, 0);
        if (!last) { if (last2) { VMW(4); } else { VMW(6); } }
        bar();
        mma(IC<0>{}, IC<1>{});
        if (!last) { readA(t + 1, IC<0>{}); readB(t + 1, IC<0>{}); }
        bar();
    }

    // ---- epilogue: C/D layout col=lane&15, row=(lane>>4)*4+i ----
    const long ldcL = ldc;
    #pragma unroll
    for (int qm = 0; qm < 2; qm++)
      #pragma unroll
      for (int mi = 0; mi < 4; mi++) {
        const int row0 = rowBase + qm * 128 + wr * 64 + mi * 16 + lg * 4;
        #pragma unroll
        for (int qn = 0; qn < 2; qn++)
          #pragma unroll
          for (int ni = 0; ni < 2; ni++) {
            const int col = colBase + qn * 128 + wc * 32 + ni * 16 + lr;
            const float bv = bias[col];
            #pragma unroll
            for (int i = 0; i < 4; i++) {
                float v = acc[qm][qn][mi][ni][i] + bv;
                if (ACT == 1) v = v > 0.f ? v : expm1f(v);
                C[(long)(row0 + i) * ldcL + col] = __float2bfloat16(v);
            }
          }
      }
}

// ---------------------------------------------------------------------------
// fp32 -> bf16 convert (vectorized, 8 elems/thread)
// ---------------------------------------------------------------------------
__global__ __launch_bounds__(256)
void cvt_k(const float* __restrict__ in, bf16* __restrict__ out)
{
    const long i = ((long)blockIdx.x * 256 + threadIdx.x) * 8;
    float4 u = *(const float4*)(in + i);
    float4 v = *(const float4*)(in + i + 4);
    bf16 t[8];
    t[0] = __float2bfloat16(u.x); t[1] = __float2bfloat16(u.y);
    t[2] = __float2bfloat16(u.z); t[3] = __float2bfloat16(u.w);
    t[4] = __float2bfloat16(v.x); t[5] = __float2bfloat16(v.y);
    t[6] = __float2bfloat16(v.z); t[7] = __float2bfloat16(v.w);
    *(short8*)(out + i) = *(short8*)t;
}

// ---------------------------------------------------------------------------
// transpose + convert: in f32 [R][R] row-major -> out bf16 transposed.
// ---------------------------------------------------------------------------
struct TPtrs { const float* s[4]; bf16* d[4]; };

__global__ __launch_bounds__(256)
void transpose_cvt_k(TPtrs p, int R, int nsub)
{
    const int z = blockIdx.z;
    const int widx = z / nsub, sub = z - widx * nsub;
    const float* __restrict__ in = p.s[widx] + (long)sub * R * R;
    bf16* __restrict__ outp = p.d[widx] + (long)sub * R * R;

    __shared__ float tile[32][33];
    const int c0 = blockIdx.x * 32, r0 = blockIdx.y * 32;
    const int tx = threadIdx.x & 31, ty = threadIdx.x >> 5;
    #pragma unroll
    for (int i = 0; i < 4; i++)
        tile[ty + i * 8][tx] = in[(long)(r0 + ty + i * 8) * R + c0 + tx];
    __syncthreads();
    #pragma unroll
    for (int i = 0; i < 4; i++)
        outp[(long)(c0 + ty + i * 8) * R + r0 + tx] = __float2bfloat16(tile[tx][ty + i * 8]);
}

// ---------------------------------------------------------------------------
DEV float2 block_reduce2_bcast(float a, float b, float* ldsr)
{
    const int lane = threadIdx.x & 63, wid = threadIdx.x >> 6;
    #pragma unroll
    for (int off = 32; off > 0; off >>= 1) {
        a += __shfl_down(a, off, 64);
        b += __shfl_down(b, off, 64);
    }
    __syncthreads();
    if (lane == 0) { ldsr[wid] = a; ldsr[wid + 4] = b; }
    __syncthreads();
    float2 rr;
    rr.x = ldsr[0] + ldsr[1] + ldsr[2] + ldsr[3];
    rr.y = ldsr[4] + ldsr[5] + ldsr[6] + ldsr[7];
    return rr;
}

// ---------------------------------------------------------------------------
// c = LN(x_flat + sigmoid(e4)*e5); w = softmax over n per (b, d)
// ---------------------------------------------------------------------------
__global__ __launch_bounds__(256)
void ln_softmax_k(const float* __restrict__ x,
                  const bf16* __restrict__ e4, const bf16* __restrict__ e5,
                  const float* __restrict__ gamma, const float* __restrict__ beta,
                  bf16* __restrict__ w)
{
    const int b = blockIdx.x, d = threadIdx.x;
    const long base = (long)b * 4096;
    __shared__ float red[8];

    float s[16];
    float sum = 0.f, sumsq = 0.f;
    #pragma unroll
    for (int n = 0; n < 16; n++) {
        const long idx = base + n * 256 + d;
        float g4 = __bfloat162float(e4[idx]);
        float g5 = __bfloat162float(e5[idx]);
        float v = x[idx] + g5 / (1.f + expf(-g4));
        s[n] = v; sum += v; sumsq += v * v;
    }
    float2 t = block_reduce2_bcast(sum, sumsq, red);
    const float mean = t.x * (1.f / 4096.f);
    const float var  = t.y * (1.f / 4096.f) - mean * mean;
    const float rstd = rsqrtf(var + 1e-5f);

    float mx = -1e30f;
    #pragma unroll
    for (int n = 0; n < 16; n++) {
        float c = (s[n] - mean) * rstd * gamma[n * 256 + d] + beta[n * 256 + d];
        s[n] = c; mx = fmaxf(mx, c);
    }
    float denom = 0.f;
    #pragma unroll
    for (int n = 0; n < 16; n++) { float e = expf(s[n] - mx); s[n] = e; denom += e; }
    const float rden = 1.f / denom;
    #pragma unroll
    for (int n = 0; n < 16; n++)
        w[base + n * 256 + d] = __float2bfloat16(s[n] * rden);
}

// ---------------------------------------------------------------------------
// out[b,d] = sum_n w[b,n,d] * LN_n(x[b,n,:] + sigmoid(e4v)*e5v)[d]
// ---------------------------------------------------------------------------
__global__ __launch_bounds__(256)
void combine_k(const float* __restrict__ x,
               const bf16* __restrict__ e4v, const bf16* __restrict__ e5v,
               const bf16* __restrict__ w,
               const float* __restrict__ vlng, const float* __restrict__ vlnb,
               float* __restrict__ out)
{
    const int b = blockIdx.x, d = threadIdx.x;
    const long base = (long)b * 4096;
    __shared__ float red[8];
    float acc = 0.f;
    for (int n = 0; n < 16; n++) {
        const long idx = base + n * 256 + d;
        float g4 = __bfloat162float(e4v[idx]);
        float g5 = __bfloat162float(e5v[idx]);
        float v = x[idx] + g5 / (1.f + expf(-g4));
        float2 t = block_reduce2_bcast(v, v * v, red);
        const float mean = t.x * (1.f / 256.f);
        const float var  = t.y * (1.f / 256.f) - mean * mean;
        const float yv = (v - mean) * rsqrtf(var + 1e-5f) * vlng[n * 256 + d] + vlnb[n * 256 + d];
        acc += __bfloat162float(w[idx]) * yv;
    }
    out[(long)b * 256 + d] = acc;
}

// ---------------------------------------------------------------------------
extern "C" void kernel_launch(void* const* d_in, const int* in_sizes, int n_in,
                              void* d_out, int out_size, void* d_ws, size_t ws_size,
                              hipStream_t stream)
{
    const float* x    = (const float*)d_in[0];
    const float* vW2  = (const float*)d_in[1];
    const float* vb2  = (const float*)d_in[2];
    const float* vW1  = (const float*)d_in[3];
    const float* vb1  = (const float*)d_in[4];
    const float* vW4  = (const float*)d_in[5];
    const float* vb4  = (const float*)d_in[6];
    const float* vW5  = (const float*)d_in[7];
    const float* vb5  = (const float*)d_in[8];
    const float* vlng = (const float*)d_in[9];
    const float* vlnb = (const float*)d_in[10];
    const float* cW2  = (const float*)d_in[11];
    const float* cb2  = (const float*)d_in[12];
    const float* cW1  = (const float*)d_in[13];
    const float* cb1  = (const float*)d_in[14];
    const float* cW4  = (const float*)d_in[15];
    const float* cb4  = (const float*)d_in[16];
    const float* cW5  = (const float*)d_in[17];
    const float* cb5  = (const float*)d_in[18];
    const float* clng = (const float*)d_in[19];
    const float* clnb = (const float*)d_in[20];
    float* out = (float*)d_out;
    (void)n_in; (void)out_size; (void)ws_size;

    const int NB = in_sizes[0] / 4096;       // batch rows (4096)
    const long XF = (long)NB * 4096;

    char* ws = (char*)d_ws;
    size_t off = 0;
    auto alloc = [&](size_t bytes) {
        char* p = ws + off;
        off += (bytes + 255) & ~(size_t)255;
        return p;
    };
    bf16* xb   = (bf16*)alloc(XF * 2);
    bf16* cW2t = (bf16*)alloc(4096L * 4096 * 2);
    bf16* cW1t = (bf16*)alloc(4096L * 4096 * 2);
    bf16* cW4t = (bf16*)alloc(4096L * 4096 * 2);
    bf16* cW5t = (bf16*)alloc(4096L * 4096 * 2);
    bf16* vW2t = (bf16*)alloc(16L * 256 * 256 * 2);
    bf16* vW1t = (bf16*)alloc(16L * 256 * 256 * 2);
    bf16* vW4t = (bf16*)alloc(16L * 256 * 256 * 2);
    bf16* vW5t = (bf16*)alloc(16L * 256 * 256 * 2);
    bf16* bufA = (bf16*)alloc(XF * 2);
    bf16* bufB = (bf16*)alloc(XF * 2);
    bf16* bufW = (bf16*)alloc(XF * 2);
    // alias dead weight buffers for the GLU pair outputs (cW2t dead after G1,
    // cW1t dead after G2; re-used again for the per-variable GLU pair)
    bf16* bufC = cW1t;   // e4 / e4v
    bf16* bufD = cW2t;   // e5 / e5v

    hipFuncSetAttribute(reinterpret_cast<const void*>(gemm256_k<0>),
                        hipFuncAttributeMaxDynamicSharedMemorySize, 131072);
    hipFuncSetAttribute(reinterpret_cast<const void*>(gemm256_k<1>),
                        hipFuncAttributeMaxDynamicSharedMemorySize, 131072);

    const int MB = NB / 256;                 // 16 row-tiles

    // 1. x -> bf16
    cvt_k<<<dim3((unsigned)(XF / 2048)), 256, 0, stream>>>(x, xb);

    // 2. big concat weights: transpose + convert
    TPtrs pb;
    pb.s[0] = cW2; pb.s[1] = cW1; pb.s[2] = cW4; pb.s[3] = cW5;
    pb.d[0] = cW2t; pb.d[1] = cW1t; pb.d[2] = cW4t; pb.d[3] = cW5t;
    transpose_cvt_k<<<dim3(128, 128, 4), 256, 0, stream>>>(pb, 4096, 1);

    // 3. per-variable weights: per-n transpose + convert
    TPtrs pv;
    pv.s[0] = vW2; pv.s[1] = vW1; pv.s[2] = vW4; pv.s[3] = vW5;
    pv.d[0] = vW2t; pv.d[1] = vW1t; pv.d[2] = vW4t; pv.d[3] = vW5t;
    transpose_cvt_k<<<dim3(8, 8, 64), 256, 0, stream>>>(pv, 256, 16);

    // 4. h = elu(xb @ cW2 + cb2) -> bufA
    gemm256_k<1><<<dim3(16, MB, 1), 512, 131072, stream>>>(
        xb, 4096, 0, cW2t, 4096, 0, cb2, 0, bufA, 4096, 0, 4096);
    // 5. e1 = bufA @ cW1 + cb1 -> bufB
    gemm256_k<0><<<dim3(16, MB, 1), 512, 131072, stream>>>(
        bufA, 4096, 0, cW1t, 4096, 0, cb1, 0, bufB, 4096, 0, 4096);
    // 6a. e4 = bufB @ cW4 + cb4 -> bufC
    gemm256_k<0><<<dim3(16, MB, 1), 512, 131072, stream>>>(
        bufB, 4096, 0, cW4t, 4096, 0, cb4, 0, bufC, 4096, 0, 4096);
    // 6b. e5 = bufB @ cW5 + cb5 -> bufD
    gemm256_k<0><<<dim3(16, MB, 1), 512, 131072, stream>>>(
        bufB, 4096, 0, cW5t, 4096, 0, cb5, 0, bufD, 4096, 0, 4096);
    // 7. c = LN(x + sig(e4)*e5); w = softmax_n(c) -> bufW
    ln_softmax_k<<<dim3(NB), 256, 0, stream>>>(x, bufC, bufD, clng, clnb, bufW);

    // 8. hv = elu(x @ vW2 + vb2) -> bufA (batched over n)
    gemm256_k<1><<<dim3(1, MB, 16), 512, 131072, stream>>>(
        xb, 4096, 256, vW2t, 256, 65536, vb2, 256, bufA, 4096, 256, 256);
    // 9. e1v = bufA @ vW1 + vb1 -> bufB
    gemm256_k<0><<<dim3(1, MB, 16), 512, 131072, stream>>>(
        bufA, 4096, 256, vW1t, 256, 65536, vb1, 256, bufB, 4096, 256, 256);
    // 10a. e4v = bufB @ vW4 + vb4 -> bufC
    gemm256_k<0><<<dim3(1, MB, 16), 512, 131072, stream>>>(
        bufB, 4096, 256, vW4t, 256, 65536, vb4, 256, bufC, 4096, 256, 256);
    // 10b. e5v = bufB @ vW5 + vb5 -> bufD
    gemm256_k<0><<<dim3(1, MB, 16), 512, 131072, stream>>>(
        bufB, 4096, 256, vW5t, 256, 65536, vb5, 256, bufD, 4096, 256, 256);

    // 11. yv = LN_n(x + sig(e4v)*e5v); out = sum_n w * yv
    combine_k<<<dim3(NB), 256, 0, stream>>>(x, bufC, bufD, bufW, vlng, vlnb, out);
}

// Round 7
// 996.976 us; speedup vs baseline: 1.1222x; 1.0720x over previous
//
#include <hip/hip_runtime.h>
#include <hip/hip_bf16.h>
#include <math.h>
#include <type_traits>

typedef __hip_bfloat16 bf16;
typedef __attribute__((ext_vector_type(8))) short short8;
typedef __attribute__((ext_vector_type(4))) float f32x4;

#define DEV __device__ __forceinline__

template<int V> using IC = std::integral_constant<int, V>;

DEV void gload_lds16(const bf16* g, bf16* l) {
    __builtin_amdgcn_global_load_lds(
        (const __attribute__((address_space(1))) void*)(g),
        (__attribute__((address_space(3))) void*)(l), 16, 0, 0);
}

#define VMW(n) do { asm volatile("s_waitcnt vmcnt(" #n ")" ::: "memory"); \
                    __builtin_amdgcn_sched_barrier(0); } while (0)
#define LKW0() do { asm volatile("s_waitcnt lgkmcnt(0)" ::: "memory"); \
                    __builtin_amdgcn_sched_barrier(0); } while (0)

// ---------------------------------------------------------------------------
// 256x256 tile, BK=64, 8 waves (2M x 4N), 4 phases / K-tile, prefetch
// distance 2 K-tiles, ONE counted vmcnt(8) per K-tile (T2+T3+T4+T5).
// C[M,N](bf16) = act(A[M,K] * Bt[N,K]^T + bias); Bt pre-transposed [N][K].
// grid = (N/256, M/256, batch), 512 threads, 128KB dynamic LDS.
// NOTE: schedule requires T = K/64 >= 4 (all uses have K >= 256).
// ---------------------------------------------------------------------------
template<int ACT>   // 0 = none, 1 = ELU
__global__ __launch_bounds__(512, 2)
void gemm256_k(const bf16* __restrict__ Am, int lda, long aBatch,
               const bf16* __restrict__ Bm, int ldb, long bBatch,
               const float* __restrict__ biasp, long biasBatch,
               bf16* __restrict__ Cm, int ldc, long cBatch, int K)
{
    extern __shared__ char lds[];
    const int bz = blockIdx.z;
    const bf16* A = Am + (long)bz * aBatch;
    const bf16* B = Bm + (long)bz * bBatch;
    const float* bias = biasp + (long)bz * biasBatch;
    bf16* C = Cm + (long)bz * cBatch;

    // T1: bijective XCD swizzle on the x-y grid (nwg multiple of 8 here)
    const int nwg = gridDim.x * gridDim.y;
    int flat = blockIdx.y * gridDim.x + blockIdx.x;
    if ((nwg & 7) == 0 && nwg >= 8) flat = (flat & 7) * (nwg >> 3) + (flat >> 3);
    const int bx = flat % gridDim.x, by = flat / gridDim.x;
    const int rowBase = by * 256, colBase = bx * 256;

    const int tid = threadIdx.x;
    const int wid = tid >> 6, lane = tid & 63;
    const int wr = wid >> 2, wc = wid & 3;     // 2x4 wave grid
    const int lr = lane & 15, lg = lane >> 4;

    // ---- staging source mapping (inverse st_16x32 swizzle on global src) ----
    const int r     = (tid >> 2) & 15;
    const int cbyte = (tid & 3) * 16;
    const int c0    = ((r & 8) ? (cbyte ^ 32) : cbyte) >> 1;   // elements
    const int srow  = (wid >> 1) * 16 + r;
    const int scol  = (wid & 1) * 32 + c0;

    const bf16* Ap = A + (long)(rowBase + srow) * lda + scol;
    const bf16* Bp = B + (long)(colBase + srow) * ldb + scol;

    // ---- swizzled ds_read frag bases (bytes within operand buffer) ----
    const int cb  = (lr & 8) ? ((lg * 16) ^ 32) : (lg * 16);
    const int aRd = wr * 8192 + lr * 64 + cb;
    const int bRd = wc * 4096 + lr * 64 + cb;

    f32x4  acc[2][2][4][2] = {};   // [qm][qn][mi][ni]
    short8 aF[2][4][2];            // [qm][mi][ks]
    short8 bF[2][2][2];            // [qn][ni][ks]

    const int T = K >> 6;

    auto stageA = [&](int tt, int h) {
        bf16* d = (bf16*)(lds + (tt & 1) * 32768 + h * 16384 + wid * 1024);
        const bf16* s = Ap + tt * 64 + (long)h * 128 * lda;
        gload_lds16(s, d);
        gload_lds16(s + (long)64 * lda, (bf16*)((char*)d + 8192));
    };
    auto stageB = [&](int tt, int h) {
        bf16* d = (bf16*)(lds + 65536 + (tt & 1) * 32768 + h * 16384 + wid * 1024);
        const bf16* s = Bp + tt * 64 + (long)h * 128 * ldb;
        gload_lds16(s, d);
        gload_lds16(s + (long)64 * ldb, (bf16*)((char*)d + 8192));
    };
    auto readA = [&](int tt, auto qmc) {
        constexpr int qm = decltype(qmc)::value;
        const char* base = lds + (tt & 1) * 32768 + qm * 16384 + aRd;
        #pragma unroll
        for (int mi = 0; mi < 4; mi++)
            #pragma unroll
            for (int ks = 0; ks < 2; ks++)
                aF[qm][mi][ks] = *(const short8*)(base + mi * 2048 + ks * 1024);
    };
    auto readB = [&](int tt, auto qnc) {
        constexpr int qn = decltype(qnc)::value;
        const char* base = lds + 65536 + (tt & 1) * 32768 + qn * 16384 + bRd;
        #pragma unroll
        for (int ni = 0; ni < 2; ni++)
            #pragma unroll
            for (int ks = 0; ks < 2; ks++)
                bF[qn][ni][ks] = *(const short8*)(base + ni * 2048 + ks * 1024);
    };
    auto mma = [&](auto qmc, auto qnc) {
        constexpr int qm = decltype(qmc)::value;
        constexpr int qn = decltype(qnc)::value;
        __builtin_amdgcn_s_setprio(1);
        #pragma unroll
        for (int mi = 0; mi < 4; mi++)
          #pragma unroll
          for (int ni = 0; ni < 2; ni++)
            #pragma unroll
            for (int ks = 0; ks < 2; ks++)
              acc[qm][qn][mi][ni] = __builtin_amdgcn_mfma_f32_16x16x32_bf16(
                  aF[qm][mi][ks], bF[qn][ni][ks], acc[qm][qn][mi][ni], 0, 0, 0);
        __builtin_amdgcn_s_setprio(0);
    };
    auto bar = [&]() {
        __builtin_amdgcn_sched_barrier(0);
        __builtin_amdgcn_s_barrier();
        __builtin_amdgcn_sched_barrier(0);
    };

    // ---- prologue: stage tiles 0 and 1 fully (16 loads); validate tile 0 ----
    stageA(0, 0); stageB(0, 0); stageA(0, 1); stageB(0, 1);
    if (T > 1) { stageA(1, 0); stageB(1, 0); stageA(1, 1); stageB(1, 1); VMW(8); }
    else       { VMW(0); }
    bar();
    readA(0, IC<0>{});     // A0(0) frags for ph0's MFMA

    // ---- main loop: phases = Q00, Q10, Q11, Q01; 1 stage/phase;
    //      single VMW(8) per K-tile at ph3 (validates all of tile t+1) ----
    for (int t = 0; t < T; t++) {
        const bool s2 = (t + 2 < T);
        // ph0: Q(0,0)
        readB(t, IC<0>{});
        if (s2) stageA(t + 2, 0);
        bar(); mma(IC<0>{}, IC<0>{}); bar();
        // ph1: Q(1,0)
        readA(t, IC<1>{});
        if (s2) stageB(t + 2, 0);
        bar(); mma(IC<1>{}, IC<0>{}); bar();
        // ph2: Q(1,1)
        readB(t, IC<1>{});
        if (s2) stageA(t + 2, 1);
        bar(); mma(IC<1>{}, IC<1>{}); bar();
        // ph3: Q(0,1); prefetch-read A0(t+1) after MFMA
        if (s2)               { stageB(t + 2, 1); VMW(8); }
        else if (t + 2 == T)  { VMW(0); }
        bar(); mma(IC<0>{}, IC<1>{});
        if (t + 1 < T) { readA(t + 1, IC<0>{}); LKW0(); }
        bar();
    }

    // ---- epilogue: C/D layout col=lane&15, row=(lane>>4)*4+i ----
    const long ldcL = ldc;
    #pragma unroll
    for (int qm = 0; qm < 2; qm++)
      #pragma unroll
      for (int mi = 0; mi < 4; mi++) {
        const int row0 = rowBase + qm * 128 + wr * 64 + mi * 16 + lg * 4;
        #pragma unroll
        for (int qn = 0; qn < 2; qn++)
          #pragma unroll
          for (int ni = 0; ni < 2; ni++) {
            const int col = colBase + qn * 128 + wc * 32 + ni * 16 + lr;
            const float bv = bias[col];
            #pragma unroll
            for (int i = 0; i < 4; i++) {
                float v = acc[qm][qn][mi][ni][i] + bv;
                if (ACT == 1) v = v > 0.f ? v : expm1f(v);
                C[(long)(row0 + i) * ldcL + col] = __float2bfloat16(v);
            }
          }
      }
}

// ---------------------------------------------------------------------------
// fp32 -> bf16 convert (vectorized, 8 elems/thread)
// ---------------------------------------------------------------------------
__global__ __launch_bounds__(256)
void cvt_k(const float* __restrict__ in, bf16* __restrict__ out)
{
    const long i = ((long)blockIdx.x * 256 + threadIdx.x) * 8;
    float4 u = *(const float4*)(in + i);
    float4 v = *(const float4*)(in + i + 4);
    bf16 t[8];
    t[0] = __float2bfloat16(u.x); t[1] = __float2bfloat16(u.y);
    t[2] = __float2bfloat16(u.z); t[3] = __float2bfloat16(u.w);
    t[4] = __float2bfloat16(v.x); t[5] = __float2bfloat16(v.y);
    t[6] = __float2bfloat16(v.z); t[7] = __float2bfloat16(v.w);
    *(short8*)(out + i) = *(short8*)t;
}

// ---------------------------------------------------------------------------
// transpose + convert: in f32 [R][R] row-major -> out bf16 transposed.
// ---------------------------------------------------------------------------
struct TPtrs { const float* s[4]; bf16* d[4]; };

__global__ __launch_bounds__(256)
void transpose_cvt_k(TPtrs p, int R, int nsub)
{
    const int z = blockIdx.z;
    const int widx = z / nsub, sub = z - widx * nsub;
    const float* __restrict__ in = p.s[widx] + (long)sub * R * R;
    bf16* __restrict__ outp = p.d[widx] + (long)sub * R * R;

    __shared__ float tile[32][33];
    const int c0 = blockIdx.x * 32, r0 = blockIdx.y * 32;
    const int tx = threadIdx.x & 31, ty = threadIdx.x >> 5;
    #pragma unroll
    for (int i = 0; i < 4; i++)
        tile[ty + i * 8][tx] = in[(long)(r0 + ty + i * 8) * R + c0 + tx];
    __syncthreads();
    #pragma unroll
    for (int i = 0; i < 4; i++)
        outp[(long)(c0 + ty + i * 8) * R + r0 + tx] = __float2bfloat16(tile[tx][ty + i * 8]);
}

// ---------------------------------------------------------------------------
DEV float2 block_reduce2_bcast(float a, float b, float* ldsr)
{
    const int lane = threadIdx.x & 63, wid = threadIdx.x >> 6;
    #pragma unroll
    for (int off = 32; off > 0; off >>= 1) {
        a += __shfl_down(a, off, 64);
        b += __shfl_down(b, off, 64);
    }
    __syncthreads();
    if (lane == 0) { ldsr[wid] = a; ldsr[wid + 4] = b; }
    __syncthreads();
    float2 rr;
    rr.x = ldsr[0] + ldsr[1] + ldsr[2] + ldsr[3];
    rr.y = ldsr[4] + ldsr[5] + ldsr[6] + ldsr[7];
    return rr;
}

DEV float glu(float g4, float g5) { return g5 / (1.f + expf(-g4)); }

// ---------------------------------------------------------------------------
// Fused final stage:
//   c  = LN_4096(x + glu(e4,e5));  w = softmax_n(c)   (thread-local over n)
//   out[b,d] = sum_n w[b,n,d] * LN_256(x[b,n,:] + glu(e4v,e5v))[d]
// one block per row b; 256 threads (thread = feature d)
// ---------------------------------------------------------------------------
__global__ __launch_bounds__(256)
void final_k(const float* __restrict__ x,
             const bf16* __restrict__ e4, const bf16* __restrict__ e5,
             const bf16* __restrict__ e4v, const bf16* __restrict__ e5v,
             const float* __restrict__ clng, const float* __restrict__ clnb,
             const float* __restrict__ vlng, const float* __restrict__ vlnb,
             float* __restrict__ out)
{
    const int b = blockIdx.x, d = threadIdx.x;
    const long base = (long)b * 4096;
    __shared__ float red[8];

    float xv[16], s[16];
    float sum = 0.f, sumsq = 0.f;
    #pragma unroll
    for (int n = 0; n < 16; n++) {
        const long idx = base + n * 256 + d;
        float xx = x[idx];
        xv[n] = xx;
        float v = xx + glu(__bfloat162float(e4[idx]), __bfloat162float(e5[idx]));
        s[n] = v; sum += v; sumsq += v * v;
    }
    float2 t = block_reduce2_bcast(sum, sumsq, red);
    const float mean = t.x * (1.f / 4096.f);
    const float var  = t.y * (1.f / 4096.f) - mean * mean;
    const float rstd = rsqrtf(var + 1e-5f);

    float mx = -1e30f;
    #pragma unroll
    for (int n = 0; n < 16; n++) {
        float c = (s[n] - mean) * rstd * clng[n * 256 + d] + clnb[n * 256 + d];
        s[n] = c; mx = fmaxf(mx, c);
    }
    float denom = 0.f;
    #pragma unroll
    for (int n = 0; n < 16; n++) { float e = expf(s[n] - mx); s[n] = e; denom += e; }
    const float rden = 1.f / denom;

    float acc = 0.f;
    for (int n = 0; n < 16; n++) {
        const long idx = base + n * 256 + d;
        float v = xv[n] + glu(__bfloat162float(e4v[idx]), __bfloat162float(e5v[idx]));
        float2 tt = block_reduce2_bcast(v, v * v, red);
        const float m2 = tt.x * (1.f / 256.f);
        const float v2 = tt.y * (1.f / 256.f) - m2 * m2;
        const float yv = (v - m2) * rsqrtf(v2 + 1e-5f) * vlng[n * 256 + d] + vlnb[n * 256 + d];
        acc += s[n] * rden * yv;
    }
    out[(long)b * 256 + d] = acc;
}

// ---------------------------------------------------------------------------
extern "C" void kernel_launch(void* const* d_in, const int* in_sizes, int n_in,
                              void* d_out, int out_size, void* d_ws, size_t ws_size,
                              hipStream_t stream)
{
    const float* x    = (const float*)d_in[0];
    const float* vW2  = (const float*)d_in[1];
    const float* vb2  = (const float*)d_in[2];
    const float* vW1  = (const float*)d_in[3];
    const float* vb1  = (const float*)d_in[4];
    const float* vW4  = (const float*)d_in[5];
    const float* vb4  = (const float*)d_in[6];
    const float* vW5  = (const float*)d_in[7];
    const float* vb5  = (const float*)d_in[8];
    const float* vlng = (const float*)d_in[9];
    const float* vlnb = (const float*)d_in[10];
    const float* cW2  = (const float*)d_in[11];
    const float* cb2  = (const float*)d_in[12];
    const float* cW1  = (const float*)d_in[13];
    const float* cb1  = (const float*)d_in[14];
    const float* cW4  = (const float*)d_in[15];
    const float* cb4  = (const float*)d_in[16];
    const float* cW5  = (const float*)d_in[17];
    const float* cb5  = (const float*)d_in[18];
    const float* clng = (const float*)d_in[19];
    const float* clnb = (const float*)d_in[20];
    float* out = (float*)d_out;
    (void)n_in; (void)out_size; (void)ws_size;

    const int NB = in_sizes[0] / 4096;       // batch rows (4096)
    const long XF = (long)NB * 4096;

    char* ws = (char*)d_ws;
    size_t off = 0;
    auto alloc = [&](size_t bytes) {
        char* p = ws + off;
        off += (bytes + 255) & ~(size_t)255;
        return p;
    };
    bf16* xb   = (bf16*)alloc(XF * 2);
    bf16* cW2t = (bf16*)alloc(4096L * 4096 * 2);
    bf16* cW1t = (bf16*)alloc(4096L * 4096 * 2);
    bf16* cW4t = (bf16*)alloc(4096L * 4096 * 2);
    bf16* cW5t = (bf16*)alloc(4096L * 4096 * 2);
    bf16* vW2t = (bf16*)alloc(16L * 256 * 256 * 2);
    bf16* vW1t = (bf16*)alloc(16L * 256 * 256 * 2);
    bf16* vW4t = (bf16*)alloc(16L * 256 * 256 * 2);
    bf16* vW5t = (bf16*)alloc(16L * 256 * 256 * 2);
    bf16* bufA = (bf16*)alloc(XF * 2);
    bf16* bufB = (bf16*)alloc(XF * 2);
    // GLU pair outputs alias dead transposed-weight buffers (liveness checked):
    bf16* e4  = cW2t;   // dead after G1
    bf16* e5  = cW1t;   // dead after G2
    bf16* e4v = cW4t;   // dead after G3
    bf16* e5v = cW5t;   // dead after G4

    hipFuncSetAttribute(reinterpret_cast<const void*>(gemm256_k<0>),
                        hipFuncAttributeMaxDynamicSharedMemorySize, 131072);
    hipFuncSetAttribute(reinterpret_cast<const void*>(gemm256_k<1>),
                        hipFuncAttributeMaxDynamicSharedMemorySize, 131072);

    const int MB = NB / 256;                 // 16 row-tiles

    // 1. x -> bf16
    cvt_k<<<dim3((unsigned)(XF / 2048)), 256, 0, stream>>>(x, xb);

    // 2. big concat weights: transpose + convert
    TPtrs pb;
    pb.s[0] = cW2; pb.s[1] = cW1; pb.s[2] = cW4; pb.s[3] = cW5;
    pb.d[0] = cW2t; pb.d[1] = cW1t; pb.d[2] = cW4t; pb.d[3] = cW5t;
    transpose_cvt_k<<<dim3(128, 128, 4), 256, 0, stream>>>(pb, 4096, 1);

    // 3. per-variable weights: per-n transpose + convert
    TPtrs pv;
    pv.s[0] = vW2; pv.s[1] = vW1; pv.s[2] = vW4; pv.s[3] = vW5;
    pv.d[0] = vW2t; pv.d[1] = vW1t; pv.d[2] = vW4t; pv.d[3] = vW5t;
    transpose_cvt_k<<<dim3(8, 8, 64), 256, 0, stream>>>(pv, 256, 16);

    // G1. h = elu(xb @ cW2 + cb2) -> bufA
    gemm256_k<1><<<dim3(16, MB, 1), 512, 131072, stream>>>(
        xb, 4096, 0, cW2t, 4096, 0, cb2, 0, bufA, 4096, 0, 4096);
    // G2. e1 = bufA @ cW1 + cb1 -> bufB
    gemm256_k<0><<<dim3(16, MB, 1), 512, 131072, stream>>>(
        bufA, 4096, 0, cW1t, 4096, 0, cb1, 0, bufB, 4096, 0, 4096);
    // G3. e4 = bufB @ cW4 + cb4
    gemm256_k<0><<<dim3(16, MB, 1), 512, 131072, stream>>>(
        bufB, 4096, 0, cW4t, 4096, 0, cb4, 0, e4, 4096, 0, 4096);
    // G4. e5 = bufB @ cW5 + cb5
    gemm256_k<0><<<dim3(16, MB, 1), 512, 131072, stream>>>(
        bufB, 4096, 0, cW5t, 4096, 0, cb5, 0, e5, 4096, 0, 4096);

    // G5. hv = elu(x @ vW2 + vb2) -> bufA (batched over n)
    gemm256_k<1><<<dim3(1, MB, 16), 512, 131072, stream>>>(
        xb, 4096, 256, vW2t, 256, 65536, vb2, 256, bufA, 4096, 256, 256);
    // G6. e1v = bufA @ vW1 + vb1 -> bufB
    gemm256_k<0><<<dim3(1, MB, 16), 512, 131072, stream>>>(
        bufA, 4096, 256, vW1t, 256, 65536, vb1, 256, bufB, 4096, 256, 256);
    // G7. e4v = bufB @ vW4 + vb4
    gemm256_k<0><<<dim3(1, MB, 16), 512, 131072, stream>>>(
        bufB, 4096, 256, vW4t, 256, 65536, vb4, 256, e4v, 4096, 256, 256);
    // G8. e5v = bufB @ vW5 + vb5
    gemm256_k<0><<<dim3(1, MB, 16), 512, 131072, stream>>>(
        bufB, 4096, 256, vW5t, 256, 65536, vb5, 256, e5v, 4096, 256, 256);

    // Final fused: concat-LN + softmax + per-var LNs + weighted combine
    final_k<<<dim3(NB), 256, 0, stream>>>(
        x, e4, e5, e4v, e5v, clng, clnb, vlng, vlnb, out);
}